// Round 12
// baseline (556.543 us; speedup 1.0000x reference)
//
#include <hip/hip_runtime.h>
#include <math.h>

#define T_OBS 256
#define NY 128
#define NITER 150

// ---- gfx9/CDNA DPP wave64 reduction: row_shr 1,2,4,8 + bcast15 + bcast31 ----
#define DPP_ROW_SHR1 0x111
#define DPP_ROW_SHR2 0x112
#define DPP_ROW_SHR4 0x114
#define DPP_ROW_SHR8 0x118
#define DPP_BCAST15  0x142
#define DPP_BCAST31  0x143

#define DPP_ADD_F32(x, ctrl) \
    (x) += __int_as_float(__builtin_amdgcn_update_dpp(0, __float_as_int(x), (ctrl), 0xf, 0xf, true))

// Interleaved dual wave-sum; returns uniform totals in a,b.
__device__ __forceinline__ void wave_sum2(float& a, float& b) {
    DPP_ADD_F32(a, DPP_ROW_SHR1); DPP_ADD_F32(b, DPP_ROW_SHR1);
    DPP_ADD_F32(a, DPP_ROW_SHR2); DPP_ADD_F32(b, DPP_ROW_SHR2);
    DPP_ADD_F32(a, DPP_ROW_SHR4); DPP_ADD_F32(b, DPP_ROW_SHR4);
    DPP_ADD_F32(a, DPP_ROW_SHR8); DPP_ADD_F32(b, DPP_ROW_SHR8);
    DPP_ADD_F32(a, DPP_BCAST15);  DPP_ADD_F32(b, DPP_BCAST15);
    DPP_ADD_F32(a, DPP_BCAST31);  DPP_ADD_F32(b, DPP_BCAST31);
    a = __int_as_float(__builtin_amdgcn_readlane(__float_as_int(a), 63));
    b = __int_as_float(__builtin_amdgcn_readlane(__float_as_int(b), 63));
}

__device__ __forceinline__ float rl(float x, int l) {
    return __int_as_float(__builtin_amdgcn_readlane(__float_as_int(x), l));
}

// ---------------- kernel 1: Y_hat = X @ W^T + b ; ep = Y - Y_hat ----------------
__global__ __launch_bounds__(128)
void pred_kernel(const float* __restrict__ X, const float* __restrict__ Y,
                 const float* __restrict__ W, const float* __restrict__ b,
                 float* __restrict__ yhat, float* __restrict__ ep) {
    __shared__ float xrow[64];
    const int t = blockIdx.x;
    const int j = threadIdx.x;
    if (j < 64) xrow[j] = X[t * 64 + j];
    __syncthreads();
    const float* wr = W + j * 64;
    float acc = 0.f;
#pragma unroll
    for (int x = 0; x < 64; ++x) acc = fmaf(xrow[x], wr[x], acc);
    const float yh = acc + b[j];
    yhat[t * NY + j] = yh;
    ep[t * NY + j] = Y[t * NY + j] - yh;
}

// ---------------- kernel 2: TWO independent DRO solves per block ----------------
// Per-scenario code is byte-identical to the verified R7 kernel. 128 blocks x
// 512 threads: waves 0-3 = scenario 2*blk, waves 4-7 = scenario 2*blk+1.
// Wave i runs on SIMD i&3, so each SIMD hosts one wave of EACH scenario —
// two independent serial chains fill each other's stall slots (2 waves/SIMD
// of real TLP, no per-scenario restructuring; grid geometry was the only
// thing capping occupancy at 1 wave/SIMD).
__global__ __launch_bounds__(512, 1)
void dro_kernel(const float* __restrict__ ep_g, const float* __restrict__ yhat_g,
                float* __restrict__ z_out,
                const float* __restrict__ d_delta, const float* __restrict__ d_gamma) {
    __shared__ float gzp[2][2][4][NY];             // [scen][buf][wave][col]
    __shared__ __align__(16) float red[2][2][8];   // [scen][buf][{S1,S2}x4]

    const int tid  = threadIdx.x;
    const int lane = tid & 63;
    const int wid  = tid >> 6;          // 0..7
    const int sloc = wid >> 2;          // scenario slot within block: 0 or 1
    const int swid = wid & 3;           // wave id within scenario: 0..3
    const int scen = blockIdx.x * 2 + sloc;   // global scenario / Z row

    // row layout: thread holds ep[stid][0..127] (128 VGPRs); ep shared by all scenarios
    const int stid = (swid << 6) | lane;      // 0..255 row within the solve
    float4 rA[32];
    {
        const float4* eg4 = (const float4*)ep_g + stid * 32;
#pragma unroll
        for (int q = 0; q < 32; ++q) rA[q] = eg4[q];
    }

    // col layout: lane holds ep[tbase+tt][j0..j0+1] (128 VGPRs)
    const int j0    = lane << 1;
    const int tbase = swid << 6;
    float2 rB[64];
#pragma unroll
    for (int tt = 0; tt < 64; ++tt)
        rB[tt] = *(const float2*)(ep_g + (tbase + tt) * NY + j0);

    const float yh0 = yhat_g[scen * NY + j0];
    const float yh1 = yhat_g[scen * NY + j0 + 1];

    // z pair in registers (each wave holds a full redundant copy across lanes)
    float z0 = 1.0f / 128.0f, z1 = 1.0f / 128.0f;
    // warm-start support indicators (carried across iterations)
    float act0 = 1.f, act1 = 1.f;

    const float delta = d_delta[0];
    const float gamma = d_gamma[0];
    float c = 0.f, eta = 0.f, lam = 0.1f;
    int buf = 0;

    for (int k = 0; k < NITER; ++k) {
        const float lr = 0.05f * __builtin_amdgcn_rsqf(1.0f + (float)k);

        // ---- phase A: r_t = ep[t,:].z - c ; z broadcast via readlane ----
        float a0 = 0.f, a1 = 0.f, a2 = 0.f, a3 = 0.f;
#pragma unroll
        for (int q = 0; q < 32; ++q) {
            const float4 e = rA[q];
            const float za = rl(z0, 2 * q);
            const float zb = rl(z1, 2 * q);
            const float zc = rl(z0, 2 * q + 1);
            const float zd = rl(z1, 2 * q + 1);
            a0 = fmaf(e.x, za, a0);
            a1 = fmaf(e.y, zb, a1);
            a2 = fmaf(e.z, zc, a2);
            a3 = fmaf(e.w, zd, a3);
        }
        const float r  = (a0 + a1) + (a2 + a3) - c;
        const float q2 = r * r - eta;
        const float aa = -lam;
        const float st = (q2 > aa) ? 1.0f : ((q2 == aa) ? 0.5f : 0.0f);
        const float wv = st * r;

        // ---- S1/S2 reduction (independent of phase B; scheduler interleaves) ----
        float s1 = st, s2 = wv;
        wave_sum2(s1, s2);
        if (lane == 0) { red[sloc][buf][swid * 2] = s1; red[sloc][buf][swid * 2 + 1] = s2; }

        // ---- phase B: per-wave partial gz over own 64 rows; w via readlane ----
        float p0 = 0.f, p1 = 0.f, p2 = 0.f, p3 = 0.f;
#pragma unroll
        for (int tt = 0; tt < 64; tt += 2) {
            const float wa = rl(wv, tt);
            const float wb = rl(wv, tt + 1);
            const float2 ea = rB[tt];
            const float2 eb = rB[tt + 1];
            p0 = fmaf(wa, ea.x, p0);
            p1 = fmaf(wa, ea.y, p1);
            p2 = fmaf(wb, eb.x, p2);
            p3 = fmaf(wb, eb.y, p3);
        }
        *(float2*)&gzp[sloc][buf][swid][j0] = make_float2(p0 + p2, p1 + p3);

        __syncthreads();   // ONE barrier: both scenarios' gzp/red[buf] visible

        // ---- all waves redundantly (per scenario): scalar updates + z step ----
        const float4 rd0 = *(const float4*)&red[sloc][buf][0];
        const float4 rd1 = *(const float4*)&red[sloc][buf][4];
        const float S1 = (rd0.x + rd0.z) + (rd1.x + rd1.z);
        const float S2 = (rd0.y + rd0.w) + (rd1.y + rd1.w);
        c   -= lr * (-(2.0f / 256.0f) * S2);
        eta -= lr * (1.0f - S1 * (1.0f / 256.0f));
        lam  = fmaxf(lam - lr * (delta - 1.0f + S1 * (1.0f / 256.0f)), 0.0f);

        const float2 g0v = *(const float2*)&gzp[sloc][buf][0][j0];
        const float2 g1v = *(const float2*)&gzp[sloc][buf][1][j0];
        const float2 g2v = *(const float2*)&gzp[sloc][buf][2][j0];
        const float2 g3v = *(const float2*)&gzp[sloc][buf][3][j0];
        const float g0 = (g0v.x + g1v.x) + (g2v.x + g3v.x);
        const float g1 = (g0v.y + g1v.y) + (g2v.y + g3v.y);
        const float v0 = z0 - lr * ((2.0f / 256.0f) * g0 - gamma * yh0);
        const float v1 = z1 - lr * ((2.0f / 256.0f) * g1 - gamma * yh1);

        // ---- simplex projection: ungated thresholding fixed point (R7) ----
        float theta = 0.f;
        for (int m = 0; m < 64; ++m) {
            float s  = act0 * v0 + act1 * v1;
            float cc = act0 + act1;
            wave_sum2(s, cc);
            theta = (s - 1.0f) * __builtin_amdgcn_rcpf(cc);
            const float n0 = (v0 > theta) ? 1.0f : 0.0f;
            const float n1 = (v1 > theta) ? 1.0f : 0.0f;
            const bool changed = (n0 != act0) || (n1 != act1);
            act0 = n0; act1 = n1;
            if (!__any(changed)) break;   // stable support == exact
        }
        z0 = fmaxf(v0 - theta, 0.f);
        z1 = fmaxf(v1 - theta, 0.f);

        buf ^= 1;
    }

    if (swid == 0) *(float2*)&z_out[scen * NY + j0] = make_float2(z0, z1);
}

extern "C" void kernel_launch(void* const* d_in, const int* in_sizes, int n_in,
                              void* d_out, int out_size, void* d_ws, size_t ws_size,
                              hipStream_t stream) {
    const float* X       = (const float*)d_in[0];   // 256*64
    const float* Y       = (const float*)d_in[1];   // 256*128
    const float* W       = (const float*)d_in[2];   // 128*64
    const float* b       = (const float*)d_in[3];   // 128
    const float* d_delta = (const float*)d_in[4];   // 1
    const float* d_gamma = (const float*)d_in[5];   // 1

    float* z_out    = (float*)d_out;                // Z_star: 256*128
    float* yhat_out = z_out + T_OBS * NY;           // Y_hat:  256*128
    float* ep_ws    = (float*)d_ws;                 // 256*128 scratch

    pred_kernel<<<T_OBS, 128, 0, stream>>>(X, Y, W, b, yhat_out, ep_ws);
    dro_kernel<<<T_OBS / 2, 512, 0, stream>>>(ep_ws, yhat_out, z_out, d_delta, d_gamma);
}

// Round 13
// 227.133 us; speedup vs baseline: 2.4503x; 2.4503x over previous
//
#include <hip/hip_runtime.h>
#include <math.h>

#define T_OBS 256
#define NY 128
#define NITER 150

// ---- gfx9/CDNA DPP wave64 reduction: row_shr 1,2,4,8 + bcast15 + bcast31 ----
#define DPP_ROW_SHR1 0x111
#define DPP_ROW_SHR2 0x112
#define DPP_ROW_SHR4 0x114
#define DPP_ROW_SHR8 0x118
#define DPP_BCAST15  0x142
#define DPP_BCAST31  0x143

#define DPP_ADD_F32(x, ctrl) \
    (x) += __int_as_float(__builtin_amdgcn_update_dpp(0, __float_as_int(x), (ctrl), 0xf, 0xf, true))

// Interleaved dual wave-sum; returns uniform totals in a,b.
__device__ __forceinline__ void wave_sum2(float& a, float& b) {
    DPP_ADD_F32(a, DPP_ROW_SHR1); DPP_ADD_F32(b, DPP_ROW_SHR1);
    DPP_ADD_F32(a, DPP_ROW_SHR2); DPP_ADD_F32(b, DPP_ROW_SHR2);
    DPP_ADD_F32(a, DPP_ROW_SHR4); DPP_ADD_F32(b, DPP_ROW_SHR4);
    DPP_ADD_F32(a, DPP_ROW_SHR8); DPP_ADD_F32(b, DPP_ROW_SHR8);
    DPP_ADD_F32(a, DPP_BCAST15);  DPP_ADD_F32(b, DPP_BCAST15);
    DPP_ADD_F32(a, DPP_BCAST31);  DPP_ADD_F32(b, DPP_BCAST31);
    a = __int_as_float(__builtin_amdgcn_readlane(__float_as_int(a), 63));
    b = __int_as_float(__builtin_amdgcn_readlane(__float_as_int(b), 63));
}

__device__ __forceinline__ float rl(float x, int l) {
    return __int_as_float(__builtin_amdgcn_readlane(__float_as_int(x), l));
}

// ---------------- kernel 1: Y_hat = X @ W^T + b ; ep = Y - Y_hat ----------------
__global__ __launch_bounds__(128)
void pred_kernel(const float* __restrict__ X, const float* __restrict__ Y,
                 const float* __restrict__ W, const float* __restrict__ b,
                 float* __restrict__ yhat, float* __restrict__ ep) {
    __shared__ float xrow[64];
    const int t = blockIdx.x;
    const int j = threadIdx.x;
    if (j < 64) xrow[j] = X[t * 64 + j];
    __syncthreads();
    const float* wr = W + j * 64;
    float acc = 0.f;
#pragma unroll
    for (int x = 0; x < 64; ++x) acc = fmaf(xrow[x], wr[x], acc);
    const float yh = acc + b[j];
    yhat[t * NY + j] = yh;
    ep[t * NY + j] = Y[t * NY + j] - yh;
}

// ---------------- kernel 2: one DRO solve per block ----------------
// Verified-best structure (R7/R11, 174.5-176.6 us): readlane broadcasts on the
// VALU pipe, ONE barrier per iteration, ungated thresholding fixed-point
// projection. Session evidence for why this is the local optimum:
//  - R2/R12: any >1 wave/SIMD arrangement fails — the 256-VGPR ep tile state
//    either duplicates issue work (split) or forces scratch spill (co-res:
//    2 waves/SIMD halves the VGPR budget to 256 < ~286 needed; R12 showed
//    VGPR capped at 128 + 15 MB scratch writes, 2.9x slower).
//  - R3: LDS-pipe broadcasts expose lgkmcnt latency at 1 wave/SIMD.
//  - R4-R6: register pinning is either unsupported (tied indirect asm),
//    aborts, or induces per-iteration v_mov shuffles (+70%).
//  - R8: v_pk_fma_f32 is half-rate fp32 on gfx950 — packing gains nothing.
//  - R9: ballot/popcount projection adds VALU<->SALU round-trip hazards.
//  - R10: broadcast pipelining / x2 unroll — compiler schedule already optimal.
__global__ __launch_bounds__(256, 1)
void dro_kernel(const float* __restrict__ ep_g, const float* __restrict__ yhat_g,
                float* __restrict__ z_out,
                const float* __restrict__ d_delta, const float* __restrict__ d_gamma) {
    __shared__ float gzp[2][4][NY];              // cross-wave partials, dbuf
    __shared__ __align__(16) float red[2][8];    // cross-wave {S1,S2}, dbuf

    const int tid  = threadIdx.x;
    const int lane = tid & 63;
    const int wid  = tid >> 6;
    const int blk  = blockIdx.x;

    // row layout: thread tid holds ep[tid][0..127] (128 VGPRs)
    float4 rA[32];
    {
        const float4* eg4 = (const float4*)ep_g + tid * 32;
#pragma unroll
        for (int q = 0; q < 32; ++q) rA[q] = eg4[q];
    }

    // col layout: lane holds ep[tbase+tt][j0..j0+1] (128 VGPRs)
    const int j0    = lane << 1;
    const int tbase = wid << 6;
    float2 rB[64];
#pragma unroll
    for (int tt = 0; tt < 64; ++tt)
        rB[tt] = *(const float2*)(ep_g + (tbase + tt) * NY + j0);

    const float yh0 = yhat_g[blk * NY + j0];
    const float yh1 = yhat_g[blk * NY + j0 + 1];

    // z pair in registers (each wave holds a full redundant copy across lanes)
    float z0 = 1.0f / 128.0f, z1 = 1.0f / 128.0f;
    // warm-start support indicators (carried across iterations)
    float act0 = 1.f, act1 = 1.f;

    const float delta = d_delta[0];
    const float gamma = d_gamma[0];
    float c = 0.f, eta = 0.f, lam = 0.1f;
    int buf = 0;

    for (int k = 0; k < NITER; ++k) {
        const float lr = 0.05f * __builtin_amdgcn_rsqf(1.0f + (float)k);

        // ---- phase A: r_t = ep[t,:].z - c ; z broadcast via readlane ----
        float a0 = 0.f, a1 = 0.f, a2 = 0.f, a3 = 0.f;
#pragma unroll
        for (int q = 0; q < 32; ++q) {
            const float4 e = rA[q];
            const float za = rl(z0, 2 * q);
            const float zb = rl(z1, 2 * q);
            const float zc = rl(z0, 2 * q + 1);
            const float zd = rl(z1, 2 * q + 1);
            a0 = fmaf(e.x, za, a0);
            a1 = fmaf(e.y, zb, a1);
            a2 = fmaf(e.z, zc, a2);
            a3 = fmaf(e.w, zd, a3);
        }
        const float r  = (a0 + a1) + (a2 + a3) - c;
        const float q2 = r * r - eta;
        const float aa = -lam;
        const float st = (q2 > aa) ? 1.0f : ((q2 == aa) ? 0.5f : 0.0f);
        const float wv = st * r;

        // ---- S1/S2 reduction (independent of phase B; scheduler interleaves) ----
        float s1 = st, s2 = wv;
        wave_sum2(s1, s2);
        if (lane == 0) { red[buf][wid * 2] = s1; red[buf][wid * 2 + 1] = s2; }

        // ---- phase B: per-wave partial gz over own 64 rows; w via readlane ----
        float p0 = 0.f, p1 = 0.f, p2 = 0.f, p3 = 0.f;
#pragma unroll
        for (int tt = 0; tt < 64; tt += 2) {
            const float wa = rl(wv, tt);
            const float wb = rl(wv, tt + 1);
            const float2 ea = rB[tt];
            const float2 eb = rB[tt + 1];
            p0 = fmaf(wa, ea.x, p0);
            p1 = fmaf(wa, ea.y, p1);
            p2 = fmaf(wb, eb.x, p2);
            p3 = fmaf(wb, eb.y, p3);
        }
        *(float2*)&gzp[buf][wid][j0] = make_float2(p0 + p2, p1 + p3);

        __syncthreads();   // the ONE barrier: gzp[buf] + red[buf] visible

        // ---- all waves redundantly: scalar updates + z step + projection ----
        const float4 rd0 = *(const float4*)&red[buf][0];
        const float4 rd1 = *(const float4*)&red[buf][4];
        const float S1 = (rd0.x + rd0.z) + (rd1.x + rd1.z);
        const float S2 = (rd0.y + rd0.w) + (rd1.y + rd1.w);
        c   -= lr * (-(2.0f / 256.0f) * S2);
        eta -= lr * (1.0f - S1 * (1.0f / 256.0f));
        lam  = fmaxf(lam - lr * (delta - 1.0f + S1 * (1.0f / 256.0f)), 0.0f);

        const float2 g0v = *(const float2*)&gzp[buf][0][j0];
        const float2 g1v = *(const float2*)&gzp[buf][1][j0];
        const float2 g2v = *(const float2*)&gzp[buf][2][j0];
        const float2 g3v = *(const float2*)&gzp[buf][3][j0];
        const float g0 = (g0v.x + g1v.x) + (g2v.x + g3v.x);
        const float g1 = (g0v.y + g1v.y) + (g2v.y + g3v.y);
        const float v0 = z0 - lr * ((2.0f / 256.0f) * g0 - gamma * yh0);
        const float v1 = z1 - lr * ((2.0f / 256.0f) * g1 - gamma * yh1);

        // ---- simplex projection: ungated thresholding fixed point.
        // theta from current support S; new S = {v > theta} (reactivation
        // allowed). Stable S == exact KKT support; summation order over the
        // converged S is identical to the gated version -> same theta bits.
        float theta = 0.f;
        for (int m = 0; m < 64; ++m) {
            float s  = act0 * v0 + act1 * v1;
            float cc = act0 + act1;
            wave_sum2(s, cc);
            theta = (s - 1.0f) * __builtin_amdgcn_rcpf(cc);
            const float n0 = (v0 > theta) ? 1.0f : 0.0f;
            const float n1 = (v1 > theta) ? 1.0f : 0.0f;
            const bool changed = (n0 != act0) || (n1 != act1);
            act0 = n0; act1 = n1;
            if (!__any(changed)) break;   // stable support == exact
        }
        z0 = fmaxf(v0 - theta, 0.f);
        z1 = fmaxf(v1 - theta, 0.f);

        buf ^= 1;
    }

    if (wid == 0) *(float2*)&z_out[blk * NY + j0] = make_float2(z0, z1);
}

extern "C" void kernel_launch(void* const* d_in, const int* in_sizes, int n_in,
                              void* d_out, int out_size, void* d_ws, size_t ws_size,
                              hipStream_t stream) {
    const float* X       = (const float*)d_in[0];   // 256*64
    const float* Y       = (const float*)d_in[1];   // 256*128
    const float* W       = (const float*)d_in[2];   // 128*64
    const float* b       = (const float*)d_in[3];   // 128
    const float* d_delta = (const float*)d_in[4];   // 1
    const float* d_gamma = (const float*)d_in[5];   // 1

    float* z_out    = (float*)d_out;                // Z_star: 256*128
    float* yhat_out = z_out + T_OBS * NY;           // Y_hat:  256*128
    float* ep_ws    = (float*)d_ws;                 // 256*128 scratch

    pred_kernel<<<T_OBS, 128, 0, stream>>>(X, Y, W, b, yhat_out, ep_ws);
    dro_kernel<<<T_OBS, 256, 0, stream>>>(ep_ws, yhat_out, z_out, d_delta, d_gamma);
}